// Round 8
// baseline (490.557 us; speedup 1.0000x reference)
//
#include <hip/hip_runtime.h>
#include <hip/hip_bf16.h>
#include <hip/hip_cooperative_groups.h>
#include <math.h>

namespace cg = cooperative_groups;

#define NP 4096     // GRID*GRID
#define NA 256      // stim channels

typedef unsigned short ushort_t;
typedef __attribute__((ext_vector_type(8))) short short8;
typedef __attribute__((ext_vector_type(4))) float f32x4;
typedef __attribute__((ext_vector_type(8))) unsigned short ushort8v;

__device__ __forceinline__ ushort_t f2bf(float x) {
    __hip_bfloat16 h = __float2bfloat16(x);
    return *reinterpret_cast<ushort_t*>(&h);
}
__device__ __forceinline__ float bf2f(ushort_t u) {
    unsigned x = ((unsigned)u) << 16;
    return __builtin_bit_cast(float, x);
}

__device__ __forceinline__ short8 pack_row(const float* rp) {
    f32x4 v0 = *(const f32x4*)(rp);
    f32x4 v1 = *(const f32x4*)(rp + 4);
    short8 r;
    r[0] = (short)f2bf(v0[0]); r[1] = (short)f2bf(v0[1]);
    r[2] = (short)f2bf(v0[2]); r[3] = (short)f2bf(v0[3]);
    r[4] = (short)f2bf(v1[0]); r[5] = (short)f2bf(v1[1]);
    r[6] = (short)f2bf(v1[2]); r[7] = (short)f2bf(v1[3]);
    return r;
}

// ---------------------------------------------------------------------------
// LDS map (147712 B total):
//  [0,131072)       lB: 8 bufs x 16KB   (aliases: phase-T lt[64][68] f32;
//                       epilogue lred_ap+lred_pa (69.6KB); lgx at +98304)
//  [131072,147456)  lgy2 [64 gi][64] f32, xor-swizzled rows
//  [147456,147712)  latt [64] f32 (phase 0 only)
// acc[pt][r] true coordinates (MFMA C/D: col=lane&15, row=(lane>>4)*4+reg):
//   p = p0 + pt*16 + r16   (output COLUMN)
//   a = a0 + asub*16 + q*4 + r   (output ROW)
// ---------------------------------------------------------------------------
template <int MODE>
__device__ __forceinline__
void gemm_phase(unsigned char* smem, int t, int p0, int a0,
                const ushort_t* __restrict__ bT,
                float sc_scale, float fac, float asig, float again,
                float* __restrict__ C, float* __restrict__ C2,
                ushort_t* __restrict__ CT,
                const ushort_t* __restrict__ numTsrc,
                float* nr)
{
    ushort_t* lB   = (ushort_t*)smem;
    float*    lgx  = (float*)(smem + 98304);    // bufs 6,7 (dead until ph=1)
    float*    lgy2 = (float*)(smem + 131072);
    float*    latt = (float*)(smem + 147456);

    const int w    = t >> 6;
    const int l    = t & 63;
    const int asub = w >> 1;          // a-subtile 0..3
    const int kh   = w & 1;           // K-half (gi parity)
    const int r16  = l & 15;
    const int q    = l >> 4;          // 0..3
    const int srow  = l >> 3;
    const int sslot = (l & 7) ^ (srow & 7);

#define STAGE(buf, tt)                                                         \
    _Pragma("unroll")                                                          \
    for (int h = 0; h < 2; ++h) {                                              \
        const ushort_t* src = bT + (size_t)(a0 + w * 8 + srow) * NP            \
                              + (2 * (tt) + h) * 64 + sslot * 8;               \
        ushort_t* dst = lB + ((buf) * 2 + h) * 4096 + (w * 8) * 64;            \
        __builtin_amdgcn_global_load_lds(                                      \
            (const __attribute__((address_space(1))) unsigned int*)src,        \
            (__attribute__((address_space(3))) unsigned int*)dst, 16, 0, 0);   \
    }

    // 4 tiles in flight while tables are computed
    STAGE(0, 0); STAGE(1, 1); STAGE(2, 2); STAGE(3, 3);

    // ---- in-block table generation (closed form, no global reads) ----
    const float step = 20.0f / 63.0f;
    const float coord = -10.0f + step * (float)l;
    #pragma unroll
    for (int i = 0; i < 8; ++i) {
        const int pl = w * 8 + i, p = p0 + pl;
        float cx = -10.0f + step * (float)(p & 63);
        float cy = -10.0f + step * (float)(p >> 6);
        float sg = (0.07f + sc_scale * sqrtf(cx * cx + cy * cy)) * fac;
        float inv = 1.0f / (2.0f * sg * sg);
        float dx = coord - cx, dy = coord - cy;
        float ex = expf(-dx * dx * inv);
        float ey = expf(-dy * dy * inv);
        float sx = ex, sy = ey;
        #pragma unroll
        for (int o = 32; o > 0; o >>= 1) {
            sx += __shfl_xor(sx, o);
            sy += __shfl_xor(sy, o);
        }
        lgx[pl * 64 + l] = ex / sx;
        // permuted+swizzled layout: consumed as f32x4 at
        // gi*64 + ((r16*4)^((gi&7)<<3)) + pt   (here l = gi)
        lgy2[l * 64 + (((pl & 15) * 4) ^ ((l & 7) << 3)) + (pl >> 4)] = ey / sy;
        if (MODE == 0 && l == 0) {
            float d2 = (cx - 3.0f) * (cx - 3.0f) + cy * cy;
            latt[pl] = again * expf(-d2 / (2.0f * asig * asig)) + 1.0f;
        }
    }
    __syncthreads();   // tables visible; also drains prologue DMA

    // B-operand fragments (gx), K-invariant, packed from LDS
    short8 gxf[4][2];
    #pragma unroll
    for (int pt = 0; pt < 4; ++pt) {
        const float* rowp = lgx + (size_t)(pt * 16 + r16) * 64;
        gxf[pt][0] = pack_row(rowp + q * 8);
        gxf[pt][1] = pack_row(rowp + 32 + q * 8);
    }
    // lgx (bufs 6,7) dead; STAGE(6)/STAGE(7) issue only after barrier(ph=0),
    // which every wave reaches after packing -> safe.

    const int n   = asub * 16 + r16;
    const int bo0 = n * 64 + ((q ^ (n & 7)) * 8);
    const int bo1 = n * 64 + (((4 + q) ^ (n & 7)) * 8);

    f32x4 acc[4];
    #pragma unroll
    for (int pt = 0; pt < 4; ++pt) acc[pt] = (f32x4){0.f, 0.f, 0.f, 0.f};

    for (int ph = 0; ph < 16; ++ph) {
        if (ph <= 13) {
            STAGE((2 * ph + 4) & 7, 2 * ph + 4);
            STAGE((2 * ph + 5) & 7, 2 * ph + 5);
            asm volatile("s_waitcnt vmcnt(8)" ::: "memory");
        } else if (ph == 14) {
            asm volatile("s_waitcnt vmcnt(4)" ::: "memory");
        } else {
            asm volatile("s_waitcnt vmcnt(0)" ::: "memory");
        }
        __builtin_amdgcn_s_barrier();

        #pragma unroll
        for (int u = 0; u < 2; ++u) {
            const int tt = 2 * ph + u;
            const ushort_t* bb = lB + ((tt & 7) * 2 + kh) * 4096;
            short8 A0 = *(const short8*)(bb + bo0);
            short8 A1 = *(const short8*)(bb + bo1);
            const int gi = 2 * tt + kh;
            f32x4 s4 = *(const f32x4*)(lgy2 + gi * 64 +
                                       ((r16 * 4) ^ ((gi & 7) << 3)));
            __builtin_amdgcn_s_setprio(1);
            #pragma unroll
            for (int pt = 0; pt < 4; ++pt) {
                f32x4 tmp = (f32x4){0.f, 0.f, 0.f, 0.f};
                tmp = __builtin_amdgcn_mfma_f32_16x16x32_bf16(A0, gxf[pt][0], tmp, 0, 0, 0);
                tmp = __builtin_amdgcn_mfma_f32_16x16x32_bf16(A1, gxf[pt][1], tmp, 0, 0, 0);
                float sc = s4[pt];
                acc[pt] += tmp * sc;
            }
            __builtin_amdgcn_s_setprio(0);
        }
    }
#undef STAGE

    // ---- epilogue v2 (FIXED mapping): dual-layout LDS reduce ----
    __syncthreads();   // all lB reads done before aliasing
    float* lred_ap = (float*)smem;              // [2][64 a][68 p]
    float* lred_pa = (float*)(smem + 34816);    // [2][64 p][68 a]

    const int a_base = asub * 16 + q * 4;       // acc[pt][r] -> a = a_base + r
    #pragma unroll
    for (int pt = 0; pt < 4; ++pt) {
        const int p_idx = pt * 16 + r16;        // acc[pt][*] -> p = p_idx
        *(f32x4*)&lred_pa[(kh * 64 + p_idx) * 68 + a_base] = acc[pt];
        #pragma unroll
        for (int r = 0; r < 4; ++r)
            lred_ap[(kh * 64 + a_base + r) * 68 + p_idx] = acc[pt][r];
    }
    __syncthreads();

    // pass A: a-major -> CT (bf16 transposed), 16B coalesced
    if (MODE != 2) {
        const int aL = t >> 3, p8 = (t & 7) * 8;
        f32x4 s0 = *(f32x4*)&lred_ap[aL * 68 + p8] +
                   *(f32x4*)&lred_ap[(64 + aL) * 68 + p8];
        f32x4 s1 = *(f32x4*)&lred_ap[aL * 68 + p8 + 4] +
                   *(f32x4*)&lred_ap[(64 + aL) * 68 + p8 + 4];
        ushort8v cv;
        if (MODE == 0) {
            f32x4 t0 = *(f32x4*)&latt[p8];
            f32x4 t1 = *(f32x4*)&latt[p8 + 4];
            s0 *= t0; s1 *= t1;
            #pragma unroll
            for (int r = 0; r < 4; ++r) {
                cv[r] = f2bf(s0[r]);
                cv[4 + r] = f2bf(s1[r]);
            }
        } else {
            ushort8v nt = *(const ushort8v*)&numTsrc[(size_t)(a0 + aL) * NP + p0 + p8];
            #pragma unroll
            for (int r = 0; r < 4; ++r) {
                cv[r] = f2bf(bf2f(nt[r]) / (s0[r] + 0.5f));
                cv[4 + r] = f2bf(bf2f(nt[4 + r]) / (s1[r] + 0.5f));
            }
        }
        *(ushort8v*)&CT[(size_t)(a0 + aL) * NP + p0 + p8] = cv;
    }

    // pass B: p-major -> C (f32), 256B/row coalesced
    {
        const int pL = t >> 3, a8 = (t & 7) * 8;
        f32x4 s0 = *(f32x4*)&lred_pa[pL * 68 + a8] +
                   *(f32x4*)&lred_pa[(64 + pL) * 68 + a8];
        f32x4 s1 = *(f32x4*)&lred_pa[pL * 68 + a8 + 4] +
                   *(f32x4*)&lred_pa[(64 + pL) * 68 + a8 + 4];
        float* cbase = C + (size_t)(p0 + pL) * NA + a0 + a8;
        if (MODE == 0) {
            float att = latt[pL];
            s0 *= att; s1 *= att;
            *(f32x4*)cbase = s0;
            *(f32x4*)(cbase + 4) = s1;
            #pragma unroll
            for (int r = 0; r < 4; ++r) { nr[r] = s0[r]; nr[4 + r] = s1[r]; }
        } else if (MODE == 1) {
            *(f32x4*)cbase = s0;                      // surround
            *(f32x4*)(cbase + 4) = s1;
            f32x4 o0, o1;
            #pragma unroll
            for (int r = 0; r < 4; ++r) {
                o0[r] = nr[r] / (s0[r] + 0.5f);
                o1[r] = nr[4 + r] / (s1[r] + 0.5f);
            }
            float* c2 = C2 + (size_t)(p0 + pL) * NA + a0 + a8;
            *(f32x4*)c2 = o0;                         // predicted_neural
            *(f32x4*)(c2 + 4) = o1;
        } else {
            *(f32x4*)cbase = s0;                      // predicted_voxel
            *(f32x4*)(cbase + 4) = s1;
        }
    }
}

// ---------------------------------------------------------------------------
// Fused cooperative kernel: transpose -> GEMM0 -> GEMM1 -> GEMM2
// 256 blocks x 512 threads, 1 block/CU (144KB LDS) -> all co-resident.
// ---------------------------------------------------------------------------
__global__ __launch_bounds__(512)
void naom_fused(const float* __restrict__ stim,
                const float* __restrict__ pscale,
                const float* __restrict__ pasig,
                const float* __restrict__ pagain,
                const float* __restrict__ pssf,
                const float* __restrict__ psff,
                float* __restrict__ num, float* __restrict__ surr,
                float* __restrict__ pn, float* __restrict__ pv,
                ushort_t* __restrict__ stimT,
                ushort_t* __restrict__ numT,
                ushort_t* __restrict__ pnT)
{
    __shared__ __align__(16) unsigned char smem[147712];
    cg::grid_group grid = cg::this_grid();
    const int t = threadIdx.x;

    // scalars -> SGPR once
    const float sc_scale = pscale[0];
    const float sc_asig  = pasig[0];
    const float sc_again = pagain[0];
    const float sc_ssf   = pssf[0];
    const float sc_sff   = psff[0];

    // ---- phase T: stim [4096 g][256 a] f32 -> stimT [256 a][4096 g] bf16 ----
    {
        const int v = blockIdx.x;
        const int g0 = (v & 63) * 64, a0t = (v >> 6) * 64;
        float* lt = (float*)smem;                 // [64][68]
        const int gr = t >> 3, ar = (t & 7) * 8;
        f32x4 x0 = *(const f32x4*)&stim[(size_t)(g0 + gr) * NA + a0t + ar];
        f32x4 x1 = *(const f32x4*)&stim[(size_t)(g0 + gr) * NA + a0t + ar + 4];
        *(f32x4*)&lt[gr * 68 + ar] = x0;
        *(f32x4*)&lt[gr * 68 + ar + 4] = x1;
        __syncthreads();
        const int a = t >> 3, c8 = (t & 7) * 8;
        ushort8v u;
        #pragma unroll
        for (int i = 0; i < 8; ++i) u[i] = f2bf(lt[(c8 + i) * 68 + a]);
        *(ushort8v*)&stimT[(size_t)(a0t + a) * NP + g0 + c8] = u;
    }
    grid.sync();

    // XCD-clustered bijective tile swizzle (same tile across all phases ->
    // producer/consumer panel locality)
    const int v   = blockIdx.x;
    const int lid = (v & 7) * 32 + (v >> 3);
    const int p0  = (lid & 63) * 64;
    const int a0  = (lid >> 6) * 64;

    float nr[8];   // num tile stash (GEMM0 -> GEMM1, identical mapping)

    gemm_phase<0>(smem, t, p0, a0, stimT, sc_scale, 1.0f, sc_asig, sc_again,
                  num, nullptr, numT, nullptr, nr);
    grid.sync();
    gemm_phase<1>(smem, t, p0, a0, numT, sc_scale, sc_ssf, 0.f, 0.f,
                  surr, pn, pnT, numT, nr);
    grid.sync();
    gemm_phase<2>(smem, t, p0, a0, pnT, sc_scale, sc_sff, 0.f, 0.f,
                  pv, nullptr, nullptr, nullptr, nr);
}

extern "C" void kernel_launch(void* const* d_in, const int* in_sizes, int n_in,
                              void* d_out, int out_size, void* d_ws, size_t ws_size,
                              hipStream_t stream)
{
    const float* stim   = (const float*)d_in[0];
    const float* pscale = (const float*)d_in[1];
    const float* pasig  = (const float*)d_in[2];
    const float* pagain = (const float*)d_in[3];
    const float* pssf   = (const float*)d_in[4];
    const float* psff   = (const float*)d_in[5];

    float* out  = (float*)d_out;
    float* num  = out;
    float* surr = out + (size_t)NP * NA;
    float* pn   = out + 2 * (size_t)NP * NA;
    float* pv   = out + 3 * (size_t)NP * NA;

    ushort_t* stimT = (ushort_t*)d_ws;                    // NA*NP bf16 (2MB)
    ushort_t* numT  = stimT + (size_t)NA * NP;            // 2MB
    ushort_t* pnT   = numT + (size_t)NA * NP;             // 2MB

    void* args[] = {
        (void*)&stim, (void*)&pscale, (void*)&pasig, (void*)&pagain,
        (void*)&pssf, (void*)&psff,
        (void*)&num, (void*)&surr, (void*)&pn, (void*)&pv,
        (void*)&stimT, (void*)&numT, (void*)&pnT
    };
    hipLaunchCooperativeKernel((const void*)naom_fused, dim3(256), dim3(512),
                               args, 0, stream);
}

// Round 9
// 69.286 us; speedup vs baseline: 7.0802x; 7.0802x over previous
//
#include <hip/hip_runtime.h>
#include <hip/hip_bf16.h>
#include <math.h>

#define NP 4096     // GRID*GRID
#define NA 256      // stim channels

typedef unsigned short ushort_t;
typedef __attribute__((ext_vector_type(8))) short short8;
typedef __attribute__((ext_vector_type(4))) float f32x4;
typedef __attribute__((ext_vector_type(8))) unsigned short ushort8v;

__device__ __forceinline__ ushort_t f2bf(float x) {
    __hip_bfloat16 h = __float2bfloat16(x);
    return *reinterpret_cast<ushort_t*>(&h);
}
__device__ __forceinline__ float bf2f(ushort_t u) {
    unsigned x = ((unsigned)u) << 16;
    return __builtin_bit_cast(float, x);
}

__device__ __forceinline__ short8 pack_row(const float* rp) {
    f32x4 v0 = *(const f32x4*)(rp);
    f32x4 v1 = *(const f32x4*)(rp + 4);
    short8 r;
    r[0] = (short)f2bf(v0[0]); r[1] = (short)f2bf(v0[1]);
    r[2] = (short)f2bf(v0[2]); r[3] = (short)f2bf(v0[3]);
    r[4] = (short)f2bf(v1[0]); r[5] = (short)f2bf(v1[1]);
    r[6] = (short)f2bf(v1[2]); r[7] = (short)f2bf(v1[3]);
    return r;
}

// ---------------------------------------------------------------------------
// stim [4096 g][256 a] f32 -> stimT [256 a][4096 g] bf16.  256 blocks x 512.
// ---------------------------------------------------------------------------
__global__ __launch_bounds__(512)
void transpose_stim(const float* __restrict__ stim, ushort_t* __restrict__ stimT)
{
    __shared__ float lt[64 * 68];
    const int t = threadIdx.x;
    const int v = blockIdx.x;
    const int g0 = (v & 63) * 64, a0 = (v >> 6) * 64;
    const int gr = t >> 3, ar = (t & 7) * 8;
    *(f32x4*)&lt[gr * 68 + ar]     = *(const f32x4*)&stim[(size_t)(g0 + gr) * NA + a0 + ar];
    *(f32x4*)&lt[gr * 68 + ar + 4] = *(const f32x4*)&stim[(size_t)(g0 + gr) * NA + a0 + ar + 4];
    __syncthreads();
    const int a = t >> 3, c8 = (t & 7) * 8;
    ushort8v u;
    #pragma unroll
    for (int i = 0; i < 8; ++i) u[i] = f2bf(lt[(c8 + i) * 68 + a]);
    *(ushort8v*)&stimT[(size_t)(a0 + a) * NP + g0 + c8] = u;
}

// ---------------------------------------------------------------------------
// Transposed-output separable-field GEMM (round-8-verified body, standalone).
// C^T[a,p] = sum_g B[g,a] * gy[p][gi] * gx[p][gj]
// LDS map (147712 B): lB 8x16KB bufs [0,131072) (lgx aliases bufs 6,7 at
// +98304 until ph=1; epilogue lred_ap/lred_pa alias lB); lgy2 at +131072
// (16KB, swizzled); latt at +147456.
// acc[pt][r]:  p = p0 + pt*16 + r16 (MFMA col),  a = a0 + asub*16 + q*4 + r.
// 8 waves = 4 a-subtiles x 2 K-halves; NBUF=8, 2 tt/phase, counted vmcnt(8).
// MODE 0: C=num=dot*att[p], CT=bf16(num)^T
// MODE 1: C=surr=dot; C2=pn=num/(surr+.5); CT=bf16(pn)^T
// MODE 2: C=pv=dot
// ---------------------------------------------------------------------------
template <int MODE>
__global__ __launch_bounds__(512)
void field_gemm(const ushort_t* __restrict__ bT,
                const float* __restrict__ pscale,
                const float* __restrict__ pasig,
                const float* __restrict__ pagain,
                const float* __restrict__ pssf,
                const float* __restrict__ psff,
                const float* __restrict__ num,      // MODE 1 input
                float* __restrict__ C,
                float* __restrict__ C2,
                ushort_t* __restrict__ CT,
                const ushort_t* __restrict__ numTsrc)
{
    __shared__ __align__(16) unsigned char smem[147712];
    ushort_t* lB   = (ushort_t*)smem;
    float*    lgx  = (float*)(smem + 98304);    // bufs 6,7 (dead until ph=1)
    float*    lgy2 = (float*)(smem + 131072);
    float*    latt = (float*)(smem + 147456);

    const int t    = threadIdx.x;
    const int w    = t >> 6;
    const int l    = t & 63;
    const int asub = w >> 1;
    const int kh   = w & 1;
    const int r16  = l & 15;
    const int q    = l >> 4;
    const int srow  = l >> 3;
    const int sslot = (l & 7) ^ (srow & 7);

    // XCD-clustered bijective tile swizzle (256 blocks, 8 XCDs)
    const int v   = blockIdx.x;
    const int lid = (v & 7) * 32 + (v >> 3);
    const int p0  = (lid & 63) * 64;
    const int a0  = (lid >> 6) * 64;

    const float sc_scale = pscale[0];
    const float fac = (MODE == 0) ? 1.0f : (MODE == 1 ? pssf[0] : psff[0]);

#define STAGE(buf, tt)                                                         \
    _Pragma("unroll")                                                          \
    for (int h = 0; h < 2; ++h) {                                              \
        const ushort_t* src = bT + (size_t)(a0 + w * 8 + srow) * NP            \
                              + (2 * (tt) + h) * 64 + sslot * 8;               \
        ushort_t* dst = lB + ((buf) * 2 + h) * 4096 + (w * 8) * 64;            \
        __builtin_amdgcn_global_load_lds(                                      \
            (const __attribute__((address_space(1))) unsigned int*)src,        \
            (__attribute__((address_space(3))) unsigned int*)dst, 16, 0, 0);   \
    }

    // 4 tiles in flight while tables are computed
    STAGE(0, 0); STAGE(1, 1); STAGE(2, 2); STAGE(3, 3);

    // ---- in-block table generation (closed form, no global reads) ----
    const float step = 20.0f / 63.0f;
    const float coord = -10.0f + step * (float)l;
    #pragma unroll
    for (int i = 0; i < 8; ++i) {
        const int pl = w * 8 + i, p = p0 + pl;
        float cx = -10.0f + step * (float)(p & 63);
        float cy = -10.0f + step * (float)(p >> 6);
        float sg = (0.07f + sc_scale * sqrtf(cx * cx + cy * cy)) * fac;
        float inv = 1.0f / (2.0f * sg * sg);
        float dx = coord - cx, dy = coord - cy;
        float ex = expf(-dx * dx * inv);
        float ey = expf(-dy * dy * inv);
        float sx = ex, sy = ey;
        #pragma unroll
        for (int o = 32; o > 0; o >>= 1) {
            sx += __shfl_xor(sx, o);
            sy += __shfl_xor(sy, o);
        }
        lgx[pl * 64 + l] = ex / sx;
        // swizzled: consumed as f32x4 at gi*64 + ((r16*4)^((gi&7)<<3)) + pt
        lgy2[l * 64 + (((pl & 15) * 4) ^ ((l & 7) << 3)) + (pl >> 4)] = ey / sy;
        if (MODE == 0 && l == 0) {
            float asig = pasig[0];
            float d2 = (cx - 3.0f) * (cx - 3.0f) + cy * cy;
            latt[pl] = pagain[0] * expf(-d2 / (2.0f * asig * asig)) + 1.0f;
        }
    }
    __syncthreads();   // tables visible; drains prologue DMA (vmcnt->0)

    // B-operand fragments (gx), K-invariant
    short8 gxf[4][2];
    #pragma unroll
    for (int pt = 0; pt < 4; ++pt) {
        const float* rowp = lgx + (size_t)(pt * 16 + r16) * 64;
        gxf[pt][0] = pack_row(rowp + q * 8);
        gxf[pt][1] = pack_row(rowp + 32 + q * 8);
    }
    // close the lgx WAR window before bufs 6,7 can be re-targeted (ph=1):
    asm volatile("s_waitcnt lgkmcnt(0)" ::: "memory");
    __builtin_amdgcn_sched_barrier(0);

    const int n   = asub * 16 + r16;
    const int bo0 = n * 64 + ((q ^ (n & 7)) * 8);
    const int bo1 = n * 64 + (((4 + q) ^ (n & 7)) * 8);

    f32x4 acc[4];
    #pragma unroll
    for (int pt = 0; pt < 4; ++pt) acc[pt] = (f32x4){0.f, 0.f, 0.f, 0.f};

    for (int ph = 0; ph < 16; ++ph) {
        if (ph <= 13) {
            STAGE((2 * ph + 4) & 7, 2 * ph + 4);
            STAGE((2 * ph + 5) & 7, 2 * ph + 5);
            asm volatile("s_waitcnt vmcnt(8)" ::: "memory");
        } else if (ph == 14) {
            asm volatile("s_waitcnt vmcnt(4)" ::: "memory");
        } else {
            asm volatile("s_waitcnt vmcnt(0)" ::: "memory");
        }
        __builtin_amdgcn_s_barrier();

        #pragma unroll
        for (int u = 0; u < 2; ++u) {
            const int tt = 2 * ph + u;
            const ushort_t* bb = lB + ((tt & 7) * 2 + kh) * 4096;
            short8 A0 = *(const short8*)(bb + bo0);
            short8 A1 = *(const short8*)(bb + bo1);
            const int gi = 2 * tt + kh;
            f32x4 s4 = *(const f32x4*)(lgy2 + gi * 64 +
                                       ((r16 * 4) ^ ((gi & 7) << 3)));
            __builtin_amdgcn_s_setprio(1);
            #pragma unroll
            for (int pt = 0; pt < 4; ++pt) {
                f32x4 tmp = (f32x4){0.f, 0.f, 0.f, 0.f};
                tmp = __builtin_amdgcn_mfma_f32_16x16x32_bf16(A0, gxf[pt][0], tmp, 0, 0, 0);
                tmp = __builtin_amdgcn_mfma_f32_16x16x32_bf16(A1, gxf[pt][1], tmp, 0, 0, 0);
                float sc = s4[pt];
                acc[pt] += tmp * sc;
            }
            __builtin_amdgcn_s_setprio(0);
        }
    }
#undef STAGE

    // ---- epilogue v2 (verified r8): dual-layout LDS reduce ----
    __syncthreads();   // all lB reads done before aliasing
    float* lred_ap = (float*)smem;              // [2][64 a][68 p]
    float* lred_pa = (float*)(smem + 34816);    // [2][64 p][68 a]

    const int a_base = asub * 16 + q * 4;       // acc[pt][r] -> a = a_base + r
    #pragma unroll
    for (int pt = 0; pt < 4; ++pt) {
        const int p_idx = pt * 16 + r16;        // acc[pt][*] -> p = p_idx
        *(f32x4*)&lred_pa[(kh * 64 + p_idx) * 68 + a_base] = acc[pt];
        #pragma unroll
        for (int r = 0; r < 4; ++r)
            lred_ap[(kh * 64 + a_base + r) * 68 + p_idx] = acc[pt][r];
    }
    __syncthreads();

    // pass A: a-major -> CT (bf16 transposed), 16B coalesced
    if (MODE != 2) {
        const int aL = t >> 3, p8 = (t & 7) * 8;
        f32x4 s0 = *(f32x4*)&lred_ap[aL * 68 + p8] +
                   *(f32x4*)&lred_ap[(64 + aL) * 68 + p8];
        f32x4 s1 = *(f32x4*)&lred_ap[aL * 68 + p8 + 4] +
                   *(f32x4*)&lred_ap[(64 + aL) * 68 + p8 + 4];
        ushort8v cv;
        if (MODE == 0) {
            f32x4 t0 = *(f32x4*)&latt[p8];
            f32x4 t1 = *(f32x4*)&latt[p8 + 4];
            s0 *= t0; s1 *= t1;
            #pragma unroll
            for (int r = 0; r < 4; ++r) {
                cv[r] = f2bf(s0[r]);
                cv[4 + r] = f2bf(s1[r]);
            }
        } else {
            ushort8v nt = *(const ushort8v*)&numTsrc[(size_t)(a0 + aL) * NP + p0 + p8];
            #pragma unroll
            for (int r = 0; r < 4; ++r) {
                cv[r] = f2bf(bf2f(nt[r]) / (s0[r] + 0.5f));
                cv[4 + r] = f2bf(bf2f(nt[4 + r]) / (s1[r] + 0.5f));
            }
        }
        *(ushort8v*)&CT[(size_t)(a0 + aL) * NP + p0 + p8] = cv;
    }

    // pass B: p-major -> C (f32), 256B/row coalesced
    {
        const int pL = t >> 3, a8 = (t & 7) * 8;
        f32x4 s0 = *(f32x4*)&lred_pa[pL * 68 + a8] +
                   *(f32x4*)&lred_pa[(64 + pL) * 68 + a8];
        f32x4 s1 = *(f32x4*)&lred_pa[pL * 68 + a8 + 4] +
                   *(f32x4*)&lred_pa[(64 + pL) * 68 + a8 + 4];
        float* cbase = C + (size_t)(p0 + pL) * NA + a0 + a8;
        if (MODE == 0) {
            float att = latt[pL];
            s0 *= att; s1 *= att;
            *(f32x4*)cbase = s0;
            *(f32x4*)(cbase + 4) = s1;
        } else if (MODE == 1) {
            *(f32x4*)cbase = s0;                      // surround
            *(f32x4*)(cbase + 4) = s1;
            const float* nb = num + (size_t)(p0 + pL) * NA + a0 + a8;
            f32x4 n0 = *(const f32x4*)nb;
            f32x4 n1 = *(const f32x4*)(nb + 4);
            f32x4 o0 = n0 / (s0 + 0.5f);
            f32x4 o1 = n1 / (s1 + 0.5f);
            float* c2 = C2 + (size_t)(p0 + pL) * NA + a0 + a8;
            *(f32x4*)c2 = o0;                         // predicted_neural
            *(f32x4*)(c2 + 4) = o1;
        } else {
            *(f32x4*)cbase = s0;                      // predicted_voxel
            *(f32x4*)(cbase + 4) = s1;
        }
    }
}

extern "C" void kernel_launch(void* const* d_in, const int* in_sizes, int n_in,
                              void* d_out, int out_size, void* d_ws, size_t ws_size,
                              hipStream_t stream)
{
    const float* stim   = (const float*)d_in[0];
    const float* pscale = (const float*)d_in[1];
    const float* pasig  = (const float*)d_in[2];
    const float* pagain = (const float*)d_in[3];
    const float* pssf   = (const float*)d_in[4];
    const float* psff   = (const float*)d_in[5];

    float* out  = (float*)d_out;
    float* num  = out;
    float* surr = out + (size_t)NP * NA;
    float* pn   = out + 2 * (size_t)NP * NA;
    float* pv   = out + 3 * (size_t)NP * NA;

    ushort_t* stimT = (ushort_t*)d_ws;                    // NA*NP bf16 (2MB)
    ushort_t* numT  = stimT + (size_t)NA * NP;            // 2MB
    ushort_t* pnT   = numT + (size_t)NA * NP;             // 2MB

    transpose_stim<<<256, 512, 0, stream>>>(stim, stimT);

    field_gemm<0><<<256, 512, 0, stream>>>(stimT, pscale, pasig, pagain, pssf,
                                           psff, nullptr, num, nullptr, numT,
                                           nullptr);
    field_gemm<1><<<256, 512, 0, stream>>>(numT, pscale, pasig, pagain, pssf,
                                           psff, num, surr, pn, pnT, numT);
    field_gemm<2><<<256, 512, 0, stream>>>(pnT, pscale, pasig, pagain, pssf,
                                           psff, nullptr, pv, nullptr, nullptr,
                                           nullptr);
}